// Round 11
// baseline (76.672 us; speedup 1.0000x reference)
//
#include <hip/hip_runtime.h>
#include <math.h>

#define BATCH 8
#define TDIM 2048
#define DDIM 512
#define SLOTB 2048       // bytes per packed row slot: [512B fp8 xq | 1024B gelu bf16 | pad]
#define NT 16            // number of 128-row tiles per batch
#define NTRI (NT*(NT+1)/2)
#define SCALE_E8M0 123   // 2^-4: compensates the x16 pre-scale on each operand

typedef unsigned short u16;
typedef float f32x4 __attribute__((ext_vector_type(4)));
typedef u16 u16x8 __attribute__((ext_vector_type(8)));
typedef int i32x4 __attribute__((ext_vector_type(4)));
typedef int i32x8 __attribute__((ext_vector_type(8)));

// fast tanh via single v_exp_f32: tanh(u) = 1 - 2/(exp(2u)+1)
__device__ __forceinline__ float tanh_fast(float u) {
    float e = __expf(2.0f * u);
    return 1.0f - 2.0f / (e + 1.0f);
}

__device__ __forceinline__ float gelu_f(float x) {
    const float c = 0.7978845608028654f; // sqrt(2/pi)
    return 0.5f * x * (1.0f + tanh_fast(c * (x + 0.044715f * x * x * x)));
}

__device__ __forceinline__ u16 f2bf(float f) {
    unsigned u = __float_as_uint(f);
    return (u16)((u + 0x7FFFu + ((u >> 16) & 1u)) >> 16); // RNE, no NaN inputs
}
__device__ __forceinline__ float bf2f(u16 h) {
    return __uint_as_float(((unsigned)h) << 16);
}

__device__ __forceinline__ float wave_sum(float v) {
    #pragma unroll
    for (int s = 1; s < 64; s <<= 1) v += __shfl_xor(v, s, 64);
    return v;
}

// ---------------- kernel 1: norms, cos_ema, fp8 xq (x_n*16) + bf16 gelu ----------------
__global__ __launch_bounds__(256) void prep_kernel(
    const float* __restrict__ x, const float* __restrict__ ema,
    char* __restrict__ slots, float* __restrict__ cosema)
{
    const int wave = threadIdx.x >> 6;
    const int lane = threadIdx.x & 63;
    const int row  = blockIdx.x * 4 + wave; // 0 .. B*T-1

    const float* xr = x + (size_t)row * DDIM + lane * 8;
    float4 v0 = *reinterpret_cast<const float4*>(xr);
    float4 v1 = *reinterpret_cast<const float4*>(xr + 4);
    const float* er = ema + lane * 8;
    float4 e0 = *reinterpret_cast<const float4*>(er);
    float4 e1 = *reinterpret_cast<const float4*>(er + 4);

    float vx[8] = {v0.x,v0.y,v0.z,v0.w,v1.x,v1.y,v1.z,v1.w};
    float ve[8] = {e0.x,e0.y,e0.z,e0.w,e1.x,e1.y,e1.z,e1.w};
    float gg[8];

    float ssx=0.f, ssg=0.f, dge=0.f, sse=0.f;
    #pragma unroll
    for (int j=0;j<8;++j) {
        float xv = vx[j];
        ssx += xv*xv;
        float gv = gelu_f(xv);
        gg[j] = gv;
        ssg += gv*gv;
        dge += gv*ve[j];
        sse += ve[j]*ve[j];
    }
    ssx = wave_sum(ssx); ssg = wave_sum(ssg);
    dge = wave_sum(dge); sse = wave_sum(sse);

    // quantize x_n * 16 to e4m3 (MX scale 2^-4 per operand restores the product)
    float invx16 = 16.0f / fmaxf(sqrtf(ssx), 1e-12f);
    float s[8];
    #pragma unroll
    for (int j=0;j<8;++j) s[j] = vx[j] * invx16;
    int q0 = __builtin_amdgcn_cvt_pk_fp8_f32(s[0], s[1], 0, false);
    q0     = __builtin_amdgcn_cvt_pk_fp8_f32(s[2], s[3], q0, true);
    int q1 = __builtin_amdgcn_cvt_pk_fp8_f32(s[4], s[5], 0, false);
    q1     = __builtin_amdgcn_cvt_pk_fp8_f32(s[6], s[7], q1, true);

    char* rowb = slots + (size_t)row * SLOTB;
    reinterpret_cast<int*>(rowb)[lane*2]     = q0;   // xq bytes [0,512)
    reinterpret_cast<int*>(rowb)[lane*2 + 1] = q1;

    u16x8 hg;
    #pragma unroll
    for (int j=0;j<8;++j) hg[j] = f2bf(gg[j]);
    *reinterpret_cast<u16x8*>(rowb + 512 + lane * 16) = hg;  // gelu bytes [512,1536)

    if (lane == 0) {
        float c = dge / (fmaxf(sqrtf(ssg), 1e-12f) * fmaxf(sqrtf(sse), 1e-12f));
        c = fminf(fmaxf(c, -1.0f), 1.0f);
        cosema[row] = c;
    }
}

// -------- kernel 2: Xn*Xn^T row-max via MX-fp8 K=128 — NO LDS, fragments from L2 --------
// Common-mistake #7 applied: per-XCD working set is 2 MB (L2-resident via the
// b = blockIdx.x % 8 XCD pinning), so LDS staging was pure overhead. Each wave
// loads its MFMA fragments directly global->VGPR: row = fragbase+roff, bytes
// klane*32 + {0,16} (per-lane offset constant, bases uniform -> saddr+imm
// addressing). Zero barriers in the K-loop, zero bank concerns, no dbuf;
// ~150 VGPR -> 3 waves/SIMD. MFMA input bits identical to the staged version.
__global__ __launch_bounds__(256, 3) void simmax_kernel(
    const char* __restrict__ slots, float* __restrict__ part)
{
    __shared__ float prow[2][128];
    __shared__ float pcol[2][128];

    const int tid  = threadIdx.x;
    const int lane = tid & 63;
    const int w    = tid >> 6;
    const int wm   = w >> 1, wn = w & 1;

    const int b = blockIdx.x & 7;        // batch == XCD (round-robin dispatch)
    // decode upper-triangular linear index -> (rt, ct), rt <= ct
    int rem = blockIdx.x >> 3, rt = 0;
    while (rem >= (NT - rt)) { rem -= (NT - rt); ++rt; }
    const int ct = rt + rem;

    const int roff  = lane & 15;
    const int klane = lane >> 4;
    const size_t laneoff = (size_t)roff * SLOTB + (size_t)klane * 32;

    // per-wave fragment base pointers (uniform base + per-lane offset)
    const char* Aw = slots + ((size_t)b * TDIM + (size_t)rt * 128 + (size_t)wm * 64) * SLOTB + laneoff;
    const char* Bw = slots + ((size_t)b * TDIM + (size_t)ct * 128 + (size_t)wn * 64) * SLOTB + laneoff;

    f32x4 zero = {0.f, 0.f, 0.f, 0.f};
    f32x4 acc[4][4];
    #pragma unroll
    for (int m=0;m<4;++m)
        #pragma unroll
        for (int n=0;n<4;++n) acc[m][n] = zero;

    #pragma unroll
    for (int ks = 0; ks < 4; ++ks) {
        i32x8 af[4], bf[4];
        #pragma unroll
        for (int m=0;m<4;++m) {
            const char* p = Aw + (size_t)m * (16*SLOTB) + ks*128;
            i32x4 lo = *reinterpret_cast<const i32x4*>(p);
            i32x4 hi = *reinterpret_cast<const i32x4*>(p + 16);
            af[m] = __builtin_shufflevector(lo, hi, 0,1,2,3,4,5,6,7);
        }
        #pragma unroll
        for (int n=0;n<4;++n) {
            const char* p = Bw + (size_t)n * (16*SLOTB) + ks*128;
            i32x4 lo = *reinterpret_cast<const i32x4*>(p);
            i32x4 hi = *reinterpret_cast<const i32x4*>(p + 16);
            bf[n] = __builtin_shufflevector(lo, hi, 0,1,2,3,4,5,6,7);
        }
        #pragma unroll
        for (int m=0;m<4;++m)
            #pragma unroll
            for (int n=0;n<4;++n)
                acc[m][n] = __builtin_amdgcn_mfma_scale_f32_16x16x128_f8f6f4(
                    af[m], bf[n], acc[m][n], 0, 0,
                    0, SCALE_E8M0, 0, SCALE_E8M0);
    }

    // ---- fused epilogue ----
    // C/D layout (m89/m91, shape-determined per m128): col = lane&15, row = (lane>>4)*4 + reg
    const int gr_base = rt*128 + wm*64;
    const int gc_base = ct*128 + wn*64;
    float rmax[4][4]; // [m][reg]  row-max (diag-masked)
    float cmax[4];    // [n]       col-max (unmasked; used when rt<ct)
    #pragma unroll
    for (int n=0;n<4;++n) cmax[n] = -2.0f;
    #pragma unroll
    for (int m=0;m<4;++m) {
        #pragma unroll
        for (int r=0;r<4;++r) {
            const int grow = gr_base + m*16 + ((lane>>4)<<2) + r;
            float mx = -2.0f;
            #pragma unroll
            for (int n=0;n<4;++n) {
                const int gcol = gc_base + n*16 + (lane & 15);
                float v = acc[m][n][r];
                cmax[n] = fmaxf(cmax[n], v);
                float vm = (grow == gcol) ? -2.0f : v;
                mx = fmaxf(mx, vm);
            }
            rmax[m][r] = mx;
        }
    }
    // row-max: butterfly across the 16-lane column group
    #pragma unroll
    for (int s = 1; s < 16; s <<= 1) {
        #pragma unroll
        for (int m=0;m<4;++m)
            #pragma unroll
            for (int r=0;r<4;++r)
                rmax[m][r] = fmaxf(rmax[m][r], __shfl_xor(rmax[m][r], s, 64));
    }
    if ((lane & 15) == 0) {
        #pragma unroll
        for (int m=0;m<4;++m)
            #pragma unroll
            for (int r=0;r<4;++r)
                prow[wn][wm*64 + m*16 + ((lane>>4)<<2) + r] = rmax[m][r];
    }
    // col-max: butterfly across the 4 row-groups
    #pragma unroll
    for (int s = 16; s < 64; s <<= 1) {
        #pragma unroll
        for (int n=0;n<4;++n)
            cmax[n] = fmaxf(cmax[n], __shfl_xor(cmax[n], s, 64));
    }
    if (lane < 16) {
        #pragma unroll
        for (int n=0;n<4;++n)
            pcol[wm][wn*64 + n*16 + lane] = cmax[n];
    }
    __syncthreads();
    if (tid < 128) {
        float rv = fmaxf(prow[0][tid], prow[1][tid]);
        part[((size_t)b*NT + ct)*TDIM + (size_t)rt*128 + tid] = rv;
        if (rt != ct) {
            float cv = fmaxf(pcol[0][tid], pcol[1][tid]);
            part[((size_t)b*NT + rt)*TDIM + (size_t)ct*128 + tid] = cv;
        }
    }
}

// ---------------- kernel 3: gate * cached gelu ----------------
// slots aliases d_out: row r's slot bytes [0,512)=xq (dead), [512,1536)=gelu
// bf16. Each wave reads its own row's gelu then overwrites its own slot with
// the fp32 out row — load-before-store within the wave, race-free.
__global__ __launch_bounds__(256) void finalize_kernel(
    char* slots,
    const float* __restrict__ part, const float* __restrict__ cosema,
    const float* __restrict__ p_log_tau, const float* __restrict__ p_log_sigma,
    const float* __restrict__ p_log_w)
{
    const int wave = threadIdx.x >> 6;
    const int lane = threadIdx.x & 63;
    const int row  = blockIdx.x * 4 + wave;
    const int b = row >> 11;     // /2048
    const int t = row & 2047;

    const float tau   = __expf(p_log_tau[0]);
    const float sigma = log1pf(__expf(p_log_sigma[0])); // softplus
    const float wgt   = log1pf(__expf(p_log_w[0]));

    float nn = -2.0f;
    #pragma unroll
    for (int ctile = 0; ctile < NT; ++ctile)
        nn = fmaxf(nn, part[((size_t)b*NT + ctile)*TDIM + t]);
    nn = fminf(fmaxf(nn, -1.0f), 1.0f);

    const float novelty  = (1.0f - nn) * 0.5f;
    const float surprise = tanh_fast(sigma * novelty);
    const float gate = __expf(-tau * cosema[row]) * (1.0f + wgt * surprise);

    char* rowb = slots + (size_t)row * SLOTB;
    u16x8 hg = *reinterpret_cast<const u16x8*>(rowb + 512 + lane * 16);
    float4 o0, o1;
    o0.x = bf2f(hg[0]) * gate; o0.y = bf2f(hg[1]) * gate;
    o0.z = bf2f(hg[2]) * gate; o0.w = bf2f(hg[3]) * gate;
    o1.x = bf2f(hg[4]) * gate; o1.y = bf2f(hg[5]) * gate;
    o1.z = bf2f(hg[6]) * gate; o1.w = bf2f(hg[7]) * gate;
    float* orow = reinterpret_cast<float*>(rowb) + lane * 8;
    *reinterpret_cast<float4*>(orow)     = o0;
    *reinterpret_cast<float4*>(orow + 4) = o1;
}

extern "C" void kernel_launch(void* const* d_in, const int* in_sizes, int n_in,
                              void* d_out, int out_size, void* d_ws, size_t ws_size,
                              hipStream_t stream) {
    const float* x           = (const float*)d_in[0];
    // d_in[1] = logit_decay (unused by reference)
    const float* p_log_tau   = (const float*)d_in[2];
    const float* p_log_sigma = (const float*)d_in[3];
    const float* p_log_w     = (const float*)d_in[4];
    const float* ema         = (const float*)d_in[5];

    // d_out doubles as scratch: per-row 2048-B slots hold [fp8 xq | bf16 gelu]
    // until finalize overwrites each slot with the fp32 output row.
    char*  slots  = (char*)d_out;                      // B*T*SLOTB = 33.6 MB
    float* part   = (float*)d_ws;                      // B*NT*T*4 = 2 MB
    float* cosema = (float*)((char*)d_ws + (size_t)BATCH*NT*TDIM*sizeof(float));

    prep_kernel<<<dim3(BATCH*TDIM/4), 256, 0, stream>>>(x, ema, slots, cosema);
    simmax_kernel<<<dim3(NTRI*BATCH), 256, 0, stream>>>(slots, part);
    finalize_kernel<<<dim3(BATCH*TDIM/4), 256, 0, stream>>>(
        slots, part, cosema, p_log_tau, p_log_sigma, p_log_w);
}

// Round 12
// 52.721 us; speedup vs baseline: 1.4543x; 1.4543x over previous
//
#include <hip/hip_runtime.h>
#include <math.h>

#define BATCH 8
#define TDIM 2048
#define DDIM 512
#define SLOTB 2048       // bytes per packed row slot: [512B fp8 xq | 1024B gelu bf16 | pad]
#define NT 16            // number of 128-row tiles per batch
#define NTRI (NT*(NT+1)/2)
#define SCALE_E8M0 123   // 2^-4: compensates the x16 pre-scale on each operand

typedef unsigned short u16;
typedef float f32x4 __attribute__((ext_vector_type(4)));
typedef u16 u16x8 __attribute__((ext_vector_type(8)));
typedef int i32x4 __attribute__((ext_vector_type(4)));
typedef int i32x8 __attribute__((ext_vector_type(8)));

// fast tanh via single v_exp_f32: tanh(u) = 1 - 2/(exp(2u)+1)
__device__ __forceinline__ float tanh_fast(float u) {
    float e = __expf(2.0f * u);
    return 1.0f - 2.0f / (e + 1.0f);
}

__device__ __forceinline__ float gelu_f(float x) {
    const float c = 0.7978845608028654f; // sqrt(2/pi)
    return 0.5f * x * (1.0f + tanh_fast(c * (x + 0.044715f * x * x * x)));
}

__device__ __forceinline__ u16 f2bf(float f) {
    unsigned u = __float_as_uint(f);
    return (u16)((u + 0x7FFFu + ((u >> 16) & 1u)) >> 16); // RNE, no NaN inputs
}
__device__ __forceinline__ float bf2f(u16 h) {
    return __uint_as_float(((unsigned)h) << 16);
}

__device__ __forceinline__ float wave_sum(float v) {
    #pragma unroll
    for (int s = 1; s < 64; s <<= 1) v += __shfl_xor(v, s, 64);
    return v;
}

__device__ __forceinline__ void load_lds16(const void* g, void* l) {
    __builtin_amdgcn_global_load_lds(
        (const __attribute__((address_space(1))) void*)g,
        (__attribute__((address_space(3))) void*)l, 16, 0, 0);
}

// ---------------- kernel 1: norms, cos_ema, fp8 xq (x_n*16) + bf16 gelu ----------------
// XCD-aligned mapping: batch = blockIdx % 8 (same pinning as simmax), so each
// batch's slot writes stay in the L2 that simmax will stage from.
__global__ __launch_bounds__(256) void prep_kernel(
    const float* __restrict__ x, const float* __restrict__ ema,
    char* __restrict__ slots, float* __restrict__ cosema)
{
    const int wave = threadIdx.x >> 6;
    const int lane = threadIdx.x & 63;
    const int xb   = blockIdx.x & 7;          // batch == XCD
    const int ib   = blockIdx.x >> 3;         // 0..511 within batch
    const int row  = (xb << 11) + ib * 4 + wave; // 0 .. B*T-1

    const float* xr = x + (size_t)row * DDIM + lane * 8;
    float4 v0 = *reinterpret_cast<const float4*>(xr);
    float4 v1 = *reinterpret_cast<const float4*>(xr + 4);
    const float* er = ema + lane * 8;
    float4 e0 = *reinterpret_cast<const float4*>(er);
    float4 e1 = *reinterpret_cast<const float4*>(er + 4);

    float vx[8] = {v0.x,v0.y,v0.z,v0.w,v1.x,v1.y,v1.z,v1.w};
    float ve[8] = {e0.x,e0.y,e0.z,e0.w,e1.x,e1.y,e1.z,e1.w};
    float gg[8];

    float ssx=0.f, ssg=0.f, dge=0.f, sse=0.f;
    #pragma unroll
    for (int j=0;j<8;++j) {
        float xv = vx[j];
        ssx += xv*xv;
        float gv = gelu_f(xv);
        gg[j] = gv;
        ssg += gv*gv;
        dge += gv*ve[j];
        sse += ve[j]*ve[j];
    }
    ssx = wave_sum(ssx); ssg = wave_sum(ssg);
    dge = wave_sum(dge); sse = wave_sum(sse);

    // quantize x_n * 16 to e4m3 (MX scale 2^-4 per operand restores the product)
    float invx16 = 16.0f / fmaxf(sqrtf(ssx), 1e-12f);
    float s[8];
    #pragma unroll
    for (int j=0;j<8;++j) s[j] = vx[j] * invx16;
    int q0 = __builtin_amdgcn_cvt_pk_fp8_f32(s[0], s[1], 0, false);
    q0     = __builtin_amdgcn_cvt_pk_fp8_f32(s[2], s[3], q0, true);
    int q1 = __builtin_amdgcn_cvt_pk_fp8_f32(s[4], s[5], 0, false);
    q1     = __builtin_amdgcn_cvt_pk_fp8_f32(s[6], s[7], q1, true);

    char* rowb = slots + (size_t)row * SLOTB;
    reinterpret_cast<int*>(rowb)[lane*2]     = q0;   // xq bytes [0,512)
    reinterpret_cast<int*>(rowb)[lane*2 + 1] = q1;

    u16x8 hg;
    #pragma unroll
    for (int j=0;j<8;++j) hg[j] = f2bf(gg[j]);
    *reinterpret_cast<u16x8*>(rowb + 512 + lane * 16) = hg;  // gelu bytes [512,1536)

    if (lane == 0) {
        float c = dge / (fmaxf(sqrtf(ssg), 1e-12f) * fmaxf(sqrtf(sse), 1e-12f));
        c = fminf(fmaxf(c, -1.0f), 1.0f);
        cosema[row] = c;
    }
}

// -------- kernel 2: per-batch Xn*Xn^T row-max via MX-fp8 K=128 (round-8 structure) --------
// Best measured configuration: dbuf issue-early staging + plain __syncthreads,
// 2 blocks/CU, T1 batch-per-XCD, source-granule XOR involution. NEW (bounded):
// diagonal tiles (rt==ct, A==B) skip B staging and read both fragments from sA.
__global__ __launch_bounds__(256) void simmax_kernel(
    const char* __restrict__ slots, float* __restrict__ part)
{
    __shared__ unsigned char sA[2][128*128];   // 128 rows x 128 B (fp8 K-tile 128)
    __shared__ unsigned char sB[2][128*128];
    __shared__ float prow[2][128];
    __shared__ float pcol[2][128];

    const int tid  = threadIdx.x;
    const int lane = tid & 63;
    const int w    = tid >> 6;
    const int wm   = w >> 1, wn = w & 1;

    const int b = blockIdx.x & 7;        // batch == XCD (round-robin dispatch)
    // decode upper-triangular linear index -> (rt, ct), rt <= ct
    int rem = blockIdx.x >> 3, rt = 0;
    while (rem >= (NT - rt)) { rem -= (NT - rt); ++rt; }
    const int ct = rt + rem;
    const bool diag = (rt == ct);

    const char* Ag = slots + ((size_t)b * TDIM + (size_t)rt * 128) * SLOTB;
    const char* Bg = slots + ((size_t)b * TDIM + (size_t)ct * 128) * SLOTB;

    const int srow  = tid >> 3;                                // 0..31 within chunk
    const int scolb = (((tid & 7) ^ ((tid >> 3) & 7))) * 16;   // pre-swizzled src granule (bytes)

    f32x4 zero = {0.f, 0.f, 0.f, 0.f};
    f32x4 acc[4][4];
    #pragma unroll
    for (int m=0;m<4;++m)
        #pragma unroll
        for (int n=0;n<4;++n) acc[m][n] = zero;

    const int roff  = lane & 15;
    const int sw    = roff & 7;          // read-side XOR (row&7 == roff&7)
    const int klane = lane >> 4;
    const int g0 = ((2*klane)     ^ sw) * 16;   // two 16-B granules per 32-B fragment
    const int g1 = ((2*klane + 1) ^ sw) * 16;

    auto stage = [&](int buf, int ks) {
        const int kb = ks * 128;          // 128 fp8 K-elems = 128 B
        #pragma unroll
        for (int i = 0; i < 4; ++i) {
            load_lds16(Ag + (size_t)(i*32 + srow) * SLOTB + kb + scolb, &sA[buf][i*4096 + w*1024]);
            if (!diag)
                load_lds16(Bg + (size_t)(i*32 + srow) * SLOTB + kb + scolb, &sB[buf][i*4096 + w*1024]);
        }
    };

    stage(0, 0);
    __syncthreads();                     // vmcnt(0) drain: buf0 ready

    for (int ks = 0; ks < 4; ++ks) {     // 512 / 128
        const int cur = ks & 1;
        if (ks < 3) stage(cur ^ 1, ks + 1);      // issue-early: hides under MFMA

        const unsigned char* Bbase = diag ? &sA[cur][0] : &sB[cur][0];
        i32x8 af[4], bf[4];
        #pragma unroll
        for (int m=0;m<4;++m) {
            const int base = (wm*64 + m*16 + roff) * 128;
            i32x4 lo = *reinterpret_cast<const i32x4*>(&sA[cur][base + g0]);
            i32x4 hi = *reinterpret_cast<const i32x4*>(&sA[cur][base + g1]);
            af[m] = __builtin_shufflevector(lo, hi, 0,1,2,3,4,5,6,7);
        }
        #pragma unroll
        for (int n=0;n<4;++n) {
            const int base = (wn*64 + n*16 + roff) * 128;
            i32x4 lo = *reinterpret_cast<const i32x4*>(Bbase + base + g0);
            i32x4 hi = *reinterpret_cast<const i32x4*>(Bbase + base + g1);
            bf[n] = __builtin_shufflevector(lo, hi, 0,1,2,3,4,5,6,7);
        }
        #pragma unroll
        for (int m=0;m<4;++m)
            #pragma unroll
            for (int n=0;n<4;++n)
                acc[m][n] = __builtin_amdgcn_mfma_scale_f32_16x16x128_f8f6f4(
                    af[m], bf[n], acc[m][n], 0, 0,
                    0, SCALE_E8M0, 0, SCALE_E8M0);

        __syncthreads();                 // next-tile loads drained + read/overwrite fence
    }

    // ---- fused epilogue ----
    // C/D layout (m89/m91, shape-determined per m128): col = lane&15, row = (lane>>4)*4 + reg
    const int gr_base = rt*128 + wm*64;
    const int gc_base = ct*128 + wn*64;
    float rmax[4][4]; // [m][reg]  row-max (diag-masked)
    float cmax[4];    // [n]       col-max (unmasked; used when rt<ct)
    #pragma unroll
    for (int n=0;n<4;++n) cmax[n] = -2.0f;
    #pragma unroll
    for (int m=0;m<4;++m) {
        #pragma unroll
        for (int r=0;r<4;++r) {
            const int grow = gr_base + m*16 + ((lane>>4)<<2) + r;
            float mx = -2.0f;
            #pragma unroll
            for (int n=0;n<4;++n) {
                const int gcol = gc_base + n*16 + (lane & 15);
                float v = acc[m][n][r];
                cmax[n] = fmaxf(cmax[n], v);
                float vm = (grow == gcol) ? -2.0f : v;
                mx = fmaxf(mx, vm);
            }
            rmax[m][r] = mx;
        }
    }
    // row-max: butterfly across the 16-lane column group
    #pragma unroll
    for (int s = 1; s < 16; s <<= 1) {
        #pragma unroll
        for (int m=0;m<4;++m)
            #pragma unroll
            for (int r=0;r<4;++r)
                rmax[m][r] = fmaxf(rmax[m][r], __shfl_xor(rmax[m][r], s, 64));
    }
    if ((lane & 15) == 0) {
        #pragma unroll
        for (int m=0;m<4;++m)
            #pragma unroll
            for (int r=0;r<4;++r)
                prow[wn][wm*64 + m*16 + ((lane>>4)<<2) + r] = rmax[m][r];
    }
    // col-max: butterfly across the 4 row-groups
    #pragma unroll
    for (int s = 16; s < 64; s <<= 1) {
        #pragma unroll
        for (int n=0;n<4;++n)
            cmax[n] = fmaxf(cmax[n], __shfl_xor(cmax[n], s, 64));
    }
    if (lane < 16) {
        #pragma unroll
        for (int n=0;n<4;++n)
            pcol[wm][wn*64 + n*16 + lane] = cmax[n];
    }
    __syncthreads();
    if (tid < 128) {
        float rv = fmaxf(prow[0][tid], prow[1][tid]);
        part[((size_t)b*NT + ct)*TDIM + (size_t)rt*128 + tid] = rv;
        if (rt != ct) {
            float cv = fmaxf(pcol[0][tid], pcol[1][tid]);
            part[((size_t)b*NT + rt)*TDIM + (size_t)ct*128 + tid] = cv;
        }
    }
}

// ---------------- kernel 3: gate * cached gelu ----------------
// slots aliases d_out: row r's slot bytes [0,512)=xq (dead), [512,1536)=gelu
// bf16. Each wave reads its own row's gelu then overwrites its own slot with
// the fp32 out row — load-before-store within the wave, race-free.
// XCD-aligned mapping: batch = blockIdx % 8 (reads part/gelu from this XCD's L2).
__global__ __launch_bounds__(256) void finalize_kernel(
    char* slots,
    const float* __restrict__ part, const float* __restrict__ cosema,
    const float* __restrict__ p_log_tau, const float* __restrict__ p_log_sigma,
    const float* __restrict__ p_log_w)
{
    const int wave = threadIdx.x >> 6;
    const int lane = threadIdx.x & 63;
    const int b    = blockIdx.x & 7;          // batch == XCD
    const int ib   = blockIdx.x >> 3;         // 0..511 within batch
    const int row  = (b << 11) + ib * 4 + wave;
    const int t = row & 2047;

    const float tau   = __expf(p_log_tau[0]);
    const float sigma = log1pf(__expf(p_log_sigma[0])); // softplus
    const float wgt   = log1pf(__expf(p_log_w[0]));

    float nn = -2.0f;
    #pragma unroll
    for (int ctile = 0; ctile < NT; ++ctile)
        nn = fmaxf(nn, part[((size_t)b*NT + ctile)*TDIM + t]);
    nn = fminf(fmaxf(nn, -1.0f), 1.0f);

    const float novelty  = (1.0f - nn) * 0.5f;
    const float surprise = tanh_fast(sigma * novelty);
    const float gate = __expf(-tau * cosema[row]) * (1.0f + wgt * surprise);

    char* rowb = slots + (size_t)row * SLOTB;
    u16x8 hg = *reinterpret_cast<const u16x8*>(rowb + 512 + lane * 16);
    float4 o0, o1;
    o0.x = bf2f(hg[0]) * gate; o0.y = bf2f(hg[1]) * gate;
    o0.z = bf2f(hg[2]) * gate; o0.w = bf2f(hg[3]) * gate;
    o1.x = bf2f(hg[4]) * gate; o1.y = bf2f(hg[5]) * gate;
    o1.z = bf2f(hg[6]) * gate; o1.w = bf2f(hg[7]) * gate;
    float* orow = reinterpret_cast<float*>(rowb) + lane * 8;
    *reinterpret_cast<float4*>(orow)     = o0;
    *reinterpret_cast<float4*>(orow + 4) = o1;
}

extern "C" void kernel_launch(void* const* d_in, const int* in_sizes, int n_in,
                              void* d_out, int out_size, void* d_ws, size_t ws_size,
                              hipStream_t stream) {
    const float* x           = (const float*)d_in[0];
    // d_in[1] = logit_decay (unused by reference)
    const float* p_log_tau   = (const float*)d_in[2];
    const float* p_log_sigma = (const float*)d_in[3];
    const float* p_log_w     = (const float*)d_in[4];
    const float* ema         = (const float*)d_in[5];

    // d_out doubles as scratch: per-row 2048-B slots hold [fp8 xq | bf16 gelu]
    // until finalize overwrites each slot with the fp32 output row.
    char*  slots  = (char*)d_out;                      // B*T*SLOTB = 33.6 MB
    float* part   = (float*)d_ws;                      // B*NT*T*4 = 2 MB
    float* cosema = (float*)((char*)d_ws + (size_t)BATCH*NT*TDIM*sizeof(float));

    prep_kernel<<<dim3(BATCH*TDIM/4), 256, 0, stream>>>(x, ema, slots, cosema);
    simmax_kernel<<<dim3(NTRI*BATCH), 256, 0, stream>>>(slots, part);
    finalize_kernel<<<dim3(BATCH*TDIM/4), 256, 0, stream>>>(
        slots, part, cosema, p_log_tau, p_log_sigma, p_log_w);
}

// Round 13
// 50.841 us; speedup vs baseline: 1.5081x; 1.0370x over previous
//
#include <hip/hip_runtime.h>
#include <math.h>

#define BATCH 8
#define TDIM 2048
#define DDIM 512
#define SLOTB 2048       // bytes per packed row slot: [256B fp4 xq | pad | 1024B gelu bf16 @512]
#define NT 16            // number of 128-row tiles per batch
#define NTRI (NT*(NT+1)/2)
#define SCALE_E8M0 122   // 2^-5 per operand: compensates the x32 pre-scale (2^-10 total)

typedef unsigned short u16;
typedef float f32x4 __attribute__((ext_vector_type(4)));
typedef u16 u16x8 __attribute__((ext_vector_type(8)));
typedef int i32x4 __attribute__((ext_vector_type(4)));
typedef int i32x8 __attribute__((ext_vector_type(8)));

// fast tanh via single v_exp_f32: tanh(u) = 1 - 2/(exp(2u)+1)
__device__ __forceinline__ float tanh_fast(float u) {
    float e = __expf(2.0f * u);
    return 1.0f - 2.0f / (e + 1.0f);
}

__device__ __forceinline__ float gelu_f(float x) {
    const float c = 0.7978845608028654f; // sqrt(2/pi)
    return 0.5f * x * (1.0f + tanh_fast(c * (x + 0.044715f * x * x * x)));
}

__device__ __forceinline__ u16 f2bf(float f) {
    unsigned u = __float_as_uint(f);
    return (u16)((u + 0x7FFFu + ((u >> 16) & 1u)) >> 16); // RNE, no NaN inputs
}
__device__ __forceinline__ float bf2f(u16 h) {
    return __uint_as_float(((unsigned)h) << 16);
}

__device__ __forceinline__ float wave_sum(float v) {
    #pragma unroll
    for (int s = 1; s < 64; s <<= 1) v += __shfl_xor(v, s, 64);
    return v;
}

__device__ __forceinline__ void load_lds16(const void* g, void* l) {
    __builtin_amdgcn_global_load_lds(
        (const __attribute__((address_space(1))) void*)g,
        (__attribute__((address_space(3))) void*)l, 16, 0, 0);
}

// ---------------- kernel 1: norms, cos_ema, fp4 xq (x_n*32) + bf16 gelu ----------------
// XCD-aligned mapping: batch = blockIdx % 8 (same pinning as simmax).
// fp4 e2m1 magnitudes {0,.5,1,1.5,2,3,4,6}: code = #thresholds passed (RNE bins),
// sign in bit 3. Nibble j of the lane's u32 = K-elem lane*8+j. Any consistent
// K-permutation of BOTH operands leaves the dot product invariant, so packing
// order cannot silently corrupt results.
__global__ __launch_bounds__(256) void prep_kernel(
    const float* __restrict__ x, const float* __restrict__ ema,
    char* __restrict__ slots, float* __restrict__ cosema)
{
    const int wave = threadIdx.x >> 6;
    const int lane = threadIdx.x & 63;
    const int xb   = blockIdx.x & 7;          // batch == XCD
    const int ib   = blockIdx.x >> 3;         // 0..511 within batch
    const int row  = (xb << 11) + ib * 4 + wave; // 0 .. B*T-1

    const float* xr = x + (size_t)row * DDIM + lane * 8;
    float4 v0 = *reinterpret_cast<const float4*>(xr);
    float4 v1 = *reinterpret_cast<const float4*>(xr + 4);
    const float* er = ema + lane * 8;
    float4 e0 = *reinterpret_cast<const float4*>(er);
    float4 e1 = *reinterpret_cast<const float4*>(er + 4);

    float vx[8] = {v0.x,v0.y,v0.z,v0.w,v1.x,v1.y,v1.z,v1.w};
    float ve[8] = {e0.x,e0.y,e0.z,e0.w,e1.x,e1.y,e1.z,e1.w};
    float gg[8];

    float ssx=0.f, ssg=0.f, dge=0.f, sse=0.f;
    #pragma unroll
    for (int j=0;j<8;++j) {
        float xv = vx[j];
        ssx += xv*xv;
        float gv = gelu_f(xv);
        gg[j] = gv;
        ssg += gv*gv;
        dge += gv*ve[j];
        sse += ve[j]*ve[j];
    }
    ssx = wave_sum(ssx); ssg = wave_sum(ssg);
    dge = wave_sum(dge); sse = wave_sum(sse);

    // quantize x_n * 32 to fp4 e2m1 (MFMA scales 2^-5 x 2^-5 restore the product)
    float invx32 = 32.0f / fmaxf(sqrtf(ssx), 1e-12f);
    unsigned pack = 0;
    #pragma unroll
    for (int j=0;j<8;++j) {
        float z = vx[j] * invx32;
        float a = fabsf(z);
        int c = (a>=0.25f) + (a>=0.75f) + (a>=1.25f) + (a>=1.75f)
              + (a>=2.5f)  + (a>=3.5f)  + (a>=5.0f);
        c |= (z < 0.0f) ? 8 : 0;
        pack |= (unsigned)c << (4*j);
    }
    char* rowb = slots + (size_t)row * SLOTB;
    reinterpret_cast<unsigned*>(rowb)[lane] = pack;   // fp4 bytes [0,256)

    u16x8 hg;
    #pragma unroll
    for (int j=0;j<8;++j) hg[j] = f2bf(gg[j]);
    *reinterpret_cast<u16x8*>(rowb + 512 + lane * 16) = hg;  // gelu bytes [512,1536)

    if (lane == 0) {
        float c = dge / (fmaxf(sqrtf(ssg), 1e-12f) * fmaxf(sqrtf(sse), 1e-12f));
        c = fminf(fmaxf(c, -1.0f), 1.0f);
        cosema[row] = c;
    }
}

// -------- kernel 2: Xn*Xn^T row-max via MX-fp4 K=128 (round-8 schedule, half the LDS work) --------
// fp4 halves the dominant shared-pipe terms vs fp8: 8 ds_read_b128/wave/iter
// (was 16), 16KB staged/block/iter (was 32KB), MFMA at 2x rate, 34KB LDS ->
// 3-4 blocks/CU. LDS layout is granule-major [4 granules][128 rows][16B]:
// 16-lane groups read 256B contiguous -> conflict-free with NO swizzle, and
// global_load_lds's linear dest (slot s = g*128 + row at offset s*16) maps to
// it directly. Dbuf issue-early + plain __syncthreads (best measured schedule).
__global__ __launch_bounds__(256) void simmax_kernel(
    const char* __restrict__ slots, float* __restrict__ part)
{
    __shared__ unsigned char sA[2][8192];   // [buf][granule(4)][row(128)][16B]
    __shared__ unsigned char sB[2][8192];
    __shared__ float prow[2][128];
    __shared__ float pcol[2][128];

    const int tid  = threadIdx.x;
    const int lane = tid & 63;
    const int w    = tid >> 6;
    const int wm   = w >> 1, wn = w & 1;

    const int b = blockIdx.x & 7;        // batch == XCD (round-robin dispatch)
    // decode upper-triangular linear index -> (rt, ct), rt <= ct
    int rem = blockIdx.x >> 3, rt = 0;
    while (rem >= (NT - rt)) { rem -= (NT - rt); ++rt; }
    const int ct = rt + rem;
    const bool diag = (rt == ct);

    const char* Ag = slots + ((size_t)b * TDIM + (size_t)rt * 128) * SLOTB;
    const char* Bg = slots + ((size_t)b * TDIM + (size_t)ct * 128) * SLOTB;

    f32x4 zero = {0.f, 0.f, 0.f, 0.f};
    f32x4 acc[4][4];
    #pragma unroll
    for (int m=0;m<4;++m)
        #pragma unroll
        for (int n=0;n<4;++n) acc[m][n] = zero;

    const int roff  = lane & 15;
    const int klane = lane >> 4;

    // stage: 512 granule-slots (s = g*128 + row), 2 per thread; dest = s*16
    // (linear per wave), source = row's K-step bytes [g*16, g*16+16).
    auto stage = [&](int buf, int ks) {
        const int kb = ks * 64;          // 128 fp4 K-elems = 64 B per row
        #pragma unroll
        for (int i = 0; i < 2; ++i) {
            const int s = i*256 + tid;
            const int g = s >> 7, r = s & 127;
            load_lds16(Ag + (size_t)r * SLOTB + kb + g*16, &sA[buf][i*4096 + w*1024]);
            if (!diag)
                load_lds16(Bg + (size_t)r * SLOTB + kb + g*16, &sB[buf][i*4096 + w*1024]);
        }
    };

    stage(0, 0);
    __syncthreads();                     // buf0 ready

    const i32x4 z4 = {0,0,0,0};
    for (int ks = 0; ks < 4; ++ks) {     // 512 / 128
        const int cur = ks & 1;
        if (ks < 3) stage(cur ^ 1, ks + 1);      // issue-early: hides under MFMA

        const unsigned char* Ab = &sA[cur][0];
        const unsigned char* Bb = diag ? Ab : &sB[cur][0];
        const int kbase = klane * 2048;          // granule-major: granule = klane
        i32x8 af[4], bf[4];
        #pragma unroll
        for (int m=0;m<4;++m) {
            i32x4 lo = *reinterpret_cast<const i32x4*>(Ab + kbase + (wm*64 + m*16 + roff)*16);
            af[m] = __builtin_shufflevector(lo, z4, 0,1,2,3,4,5,6,7);
        }
        #pragma unroll
        for (int n=0;n<4;++n) {
            i32x4 lo = *reinterpret_cast<const i32x4*>(Bb + kbase + (wn*64 + n*16 + roff)*16);
            bf[n] = __builtin_shufflevector(lo, z4, 0,1,2,3,4,5,6,7);
        }
        #pragma unroll
        for (int m=0;m<4;++m)
            #pragma unroll
            for (int n=0;n<4;++n)
                acc[m][n] = __builtin_amdgcn_mfma_scale_f32_16x16x128_f8f6f4(
                    af[m], bf[n], acc[m][n], 4, 4,   // cbsz=4 (FP4), blgp=4 (FP4)
                    0, SCALE_E8M0, 0, SCALE_E8M0);

        __syncthreads();                 // next-tile loads drained + read/overwrite fence
    }

    // ---- fused epilogue ----
    // C/D layout (m89/m91, shape-determined per m128): col = lane&15, row = (lane>>4)*4 + reg
    const int gr_base = rt*128 + wm*64;
    const int gc_base = ct*128 + wn*64;
    float rmax[4][4]; // [m][reg]  row-max (diag-masked)
    float cmax[4];    // [n]       col-max (unmasked; used when rt<ct)
    #pragma unroll
    for (int n=0;n<4;++n) cmax[n] = -2.0f;
    #pragma unroll
    for (int m=0;m<4;++m) {
        #pragma unroll
        for (int r=0;r<4;++r) {
            const int grow = gr_base + m*16 + ((lane>>4)<<2) + r;
            float mx = -2.0f;
            #pragma unroll
            for (int n=0;n<4;++n) {
                const int gcol = gc_base + n*16 + (lane & 15);
                float v = acc[m][n][r];
                cmax[n] = fmaxf(cmax[n], v);
                float vm = (grow == gcol) ? -2.0f : v;
                mx = fmaxf(mx, vm);
            }
            rmax[m][r] = mx;
        }
    }
    // row-max: butterfly across the 16-lane column group
    #pragma unroll
    for (int s = 1; s < 16; s <<= 1) {
        #pragma unroll
        for (int m=0;m<4;++m)
            #pragma unroll
            for (int r=0;r<4;++r)
                rmax[m][r] = fmaxf(rmax[m][r], __shfl_xor(rmax[m][r], s, 64));
    }
    if ((lane & 15) == 0) {
        #pragma unroll
        for (int m=0;m<4;++m)
            #pragma unroll
            for (int r=0;r<4;++r)
                prow[wn][wm*64 + m*16 + ((lane>>4)<<2) + r] = rmax[m][r];
    }
    // col-max: butterfly across the 4 row-groups
    #pragma unroll
    for (int s = 16; s < 64; s <<= 1) {
        #pragma unroll
        for (int n=0;n<4;++n)
            cmax[n] = fmaxf(cmax[n], __shfl_xor(cmax[n], s, 64));
    }
    if (lane < 16) {
        #pragma unroll
        for (int n=0;n<4;++n)
            pcol[wm][wn*64 + n*16 + lane] = cmax[n];
    }
    __syncthreads();
    if (tid < 128) {
        float rv = fmaxf(prow[0][tid], prow[1][tid]);
        part[((size_t)b*NT + ct)*TDIM + (size_t)rt*128 + tid] = rv;
        if (rt != ct) {
            float cv = fmaxf(pcol[0][tid], pcol[1][tid]);
            part[((size_t)b*NT + rt)*TDIM + (size_t)ct*128 + tid] = cv;
        }
    }
}

// ---------------- kernel 3: gate * cached gelu ----------------
// slots aliases d_out: row r's slot bytes [0,256)=xq (dead), [512,1536)=gelu
// bf16. Each wave reads its own row's gelu then overwrites its own slot with
// the fp32 out row — load-before-store within the wave, race-free.
// XCD-aligned mapping: batch = blockIdx % 8.
__global__ __launch_bounds__(256) void finalize_kernel(
    char* slots,
    const float* __restrict__ part, const float* __restrict__ cosema,
    const float* __restrict__ p_log_tau, const float* __restrict__ p_log_sigma,
    const float* __restrict__ p_log_w)
{
    const int wave = threadIdx.x >> 6;
    const int lane = threadIdx.x & 63;
    const int b    = blockIdx.x & 7;          // batch == XCD
    const int ib   = blockIdx.x >> 3;         // 0..511 within batch
    const int row  = (b << 11) + ib * 4 + wave;
    const int t = row & 2047;

    const float tau   = __expf(p_log_tau[0]);
    const float sigma = log1pf(__expf(p_log_sigma[0])); // softplus
    const float wgt   = log1pf(__expf(p_log_w[0]));

    float nn = -2.0f;
    #pragma unroll
    for (int ctile = 0; ctile < NT; ++ctile)
        nn = fmaxf(nn, part[((size_t)b*NT + ctile)*TDIM + t]);
    nn = fminf(fmaxf(nn, -1.0f), 1.0f);

    const float novelty  = (1.0f - nn) * 0.5f;
    const float surprise = tanh_fast(sigma * novelty);
    const float gate = __expf(-tau * cosema[row]) * (1.0f + wgt * surprise);

    char* rowb = slots + (size_t)row * SLOTB;
    u16x8 hg = *reinterpret_cast<const u16x8*>(rowb + 512 + lane * 16);
    float4 o0, o1;
    o0.x = bf2f(hg[0]) * gate; o0.y = bf2f(hg[1]) * gate;
    o0.z = bf2f(hg[2]) * gate; o0.w = bf2f(hg[3]) * gate;
    o1.x = bf2f(hg[4]) * gate; o1.y = bf2f(hg[5]) * gate;
    o1.z = bf2f(hg[6]) * gate; o1.w = bf2f(hg[7]) * gate;
    float* orow = reinterpret_cast<float*>(rowb) + lane * 8;
    *reinterpret_cast<float4*>(orow)     = o0;
    *reinterpret_cast<float4*>(orow + 4) = o1;
}

extern "C" void kernel_launch(void* const* d_in, const int* in_sizes, int n_in,
                              void* d_out, int out_size, void* d_ws, size_t ws_size,
                              hipStream_t stream) {
    const float* x           = (const float*)d_in[0];
    // d_in[1] = logit_decay (unused by reference)
    const float* p_log_tau   = (const float*)d_in[2];
    const float* p_log_sigma = (const float*)d_in[3];
    const float* p_log_w     = (const float*)d_in[4];
    const float* ema         = (const float*)d_in[5];

    // d_out doubles as scratch: per-row 2048-B slots hold [fp4 xq | bf16 gelu]
    // until finalize overwrites each slot with the fp32 output row.
    char*  slots  = (char*)d_out;                      // B*T*SLOTB = 33.6 MB
    float* part   = (float*)d_ws;                      // B*NT*T*4 = 2 MB
    float* cosema = (float*)((char*)d_ws + (size_t)BATCH*NT*TDIM*sizeof(float));

    prep_kernel<<<dim3(BATCH*TDIM/4), 256, 0, stream>>>(x, ema, slots, cosema);
    simmax_kernel<<<dim3(NTRI*BATCH), 256, 0, stream>>>(slots, part);
    finalize_kernel<<<dim3(BATCH*TDIM/4), 256, 0, stream>>>(
        slots, part, cosema, p_log_tau, p_log_sigma, p_log_w);
}

// Round 15
// 48.780 us; speedup vs baseline: 1.5718x; 1.0423x over previous
//
#include <hip/hip_runtime.h>
#include <math.h>

#define BATCH 8
#define TDIM 2048
#define DDIM 512
#define SLOTB 2048       // bytes per packed row slot: [256B fp4 xq | pad | 1024B gelu bf16 @512]
#define NT 16            // number of 128-row tiles per batch
#define NTRI (NT*(NT+1)/2)
#define SCALE_E8M0 122   // 2^-5 per operand: compensates the x32 pre-scale (2^-10 total)

typedef unsigned short u16;
typedef float f32x4 __attribute__((ext_vector_type(4)));
typedef u16 u16x8 __attribute__((ext_vector_type(8)));
typedef int i32x4 __attribute__((ext_vector_type(4)));
typedef int i32x8 __attribute__((ext_vector_type(8)));

// fast tanh via single v_exp_f32: tanh(u) = 1 - 2/(exp(2u)+1)
__device__ __forceinline__ float tanh_fast(float u) {
    float e = __expf(2.0f * u);
    return 1.0f - 2.0f / (e + 1.0f);
}

__device__ __forceinline__ float gelu_f(float x) {
    const float c = 0.7978845608028654f; // sqrt(2/pi)
    return 0.5f * x * (1.0f + tanh_fast(c * (x + 0.044715f * x * x * x)));
}

__device__ __forceinline__ u16 f2bf(float f) {
    unsigned u = __float_as_uint(f);
    return (u16)((u + 0x7FFFu + ((u >> 16) & 1u)) >> 16); // RNE, no NaN inputs
}
__device__ __forceinline__ float bf2f(u16 h) {
    return __uint_as_float(((unsigned)h) << 16);
}

__device__ __forceinline__ float wave_sum(float v) {
    #pragma unroll
    for (int s = 1; s < 64; s <<= 1) v += __shfl_xor(v, s, 64);
    return v;
}

__device__ __forceinline__ void load_lds16(const void* g, void* l) {
    __builtin_amdgcn_global_load_lds(
        (const __attribute__((address_space(1))) void*)g,
        (__attribute__((address_space(3))) void*)l, 16, 0, 0);
}

// ---------------- kernel 1: norms, cos_ema, fp4 xq (x_n*32) + bf16 gelu ----------------
// XCD-aligned mapping: batch = blockIdx % 8 (same pinning as simmax).
// fp4 e2m1 magnitudes {0,.5,1,1.5,2,3,4,6}: code = #thresholds passed (RNE bins),
// sign in bit 3. Nibble j of the lane's u32 = K-elem lane*8+j. Any consistent
// K-permutation of BOTH operands leaves the dot product invariant, so packing
// order cannot silently corrupt results.
__global__ __launch_bounds__(256) void prep_kernel(
    const float* __restrict__ x, const float* __restrict__ ema,
    char* __restrict__ slots, float* __restrict__ cosema)
{
    const int wave = threadIdx.x >> 6;
    const int lane = threadIdx.x & 63;
    const int xb   = blockIdx.x & 7;          // batch == XCD
    const int ib   = blockIdx.x >> 3;         // 0..511 within batch
    const int row  = (xb << 11) + ib * 4 + wave; // 0 .. B*T-1

    const float* xr = x + (size_t)row * DDIM + lane * 8;
    float4 v0 = *reinterpret_cast<const float4*>(xr);
    float4 v1 = *reinterpret_cast<const float4*>(xr + 4);
    const float* er = ema + lane * 8;
    float4 e0 = *reinterpret_cast<const float4*>(er);
    float4 e1 = *reinterpret_cast<const float4*>(er + 4);

    float vx[8] = {v0.x,v0.y,v0.z,v0.w,v1.x,v1.y,v1.z,v1.w};
    float ve[8] = {e0.x,e0.y,e0.z,e0.w,e1.x,e1.y,e1.z,e1.w};
    float gg[8];

    float ssx=0.f, ssg=0.f, dge=0.f, sse=0.f;
    #pragma unroll
    for (int j=0;j<8;++j) {
        float xv = vx[j];
        ssx += xv*xv;
        float gv = gelu_f(xv);
        gg[j] = gv;
        ssg += gv*gv;
        dge += gv*ve[j];
        sse += ve[j]*ve[j];
    }
    ssx = wave_sum(ssx); ssg = wave_sum(ssg);
    dge = wave_sum(dge); sse = wave_sum(sse);

    // quantize x_n * 32 to fp4 e2m1 (MFMA scales 2^-5 x 2^-5 restore the product)
    float invx32 = 32.0f / fmaxf(sqrtf(ssx), 1e-12f);
    unsigned pack = 0;
    #pragma unroll
    for (int j=0;j<8;++j) {
        float z = vx[j] * invx32;
        float a = fabsf(z);
        int c = (a>=0.25f) + (a>=0.75f) + (a>=1.25f) + (a>=1.75f)
              + (a>=2.5f)  + (a>=3.5f)  + (a>=5.0f);
        c |= (z < 0.0f) ? 8 : 0;
        pack |= (unsigned)c << (4*j);
    }
    char* rowb = slots + (size_t)row * SLOTB;
    reinterpret_cast<unsigned*>(rowb)[lane] = pack;   // fp4 bytes [0,256)

    u16x8 hg;
    #pragma unroll
    for (int j=0;j<8;++j) hg[j] = f2bf(gg[j]);
    *reinterpret_cast<u16x8*>(rowb + 512 + lane * 16) = hg;  // gelu bytes [512,1536)

    if (lane == 0) {
        float c = dge / (fmaxf(sqrtf(ssg), 1e-12f) * fmaxf(sqrtf(sse), 1e-12f));
        c = fminf(fmaxf(c, -1.0f), 1.0f);
        cosema[row] = c;
    }
}

// -------- kernel 2: Xn*Xn^T row-max via MX-fp4 K=128 — FULL-K in LDS, ONE barrier --------
// At fp4 one operand's full-K tile is 256B/row x 128 rows = 32 KB = 2048
// granule-slots = 8 slots/thread (ROUND-14 BUG: 16 iterations overflowed sA
// into sB by 32 KB -> absmax 0.25; fixed to 8). Stage everything, ONE
// __syncthreads, then all 64 MFMAs back-to-back — zero inner barriers.
// 66 KB LDS -> 2 blocks/CU: co-resident block computes while this one drains.
// Granule-major layout [G=16][row=128][16B]: 16-lane groups read 256 B
// contiguous -> conflict-free, no swizzle; global_load_lds linear dest maps
// directly (slot s = G*128+r at byte s*16; thread slot s = i*256+w*64+lane).
__global__ __launch_bounds__(256) void simmax_kernel(
    const char* __restrict__ slots, float* __restrict__ part)
{
    __shared__ unsigned char sA[32768];   // [G(16)][row(128)][16B]
    __shared__ unsigned char sB[32768];
    __shared__ float prow[2][128];
    __shared__ float pcol[2][128];

    const int tid  = threadIdx.x;
    const int lane = tid & 63;
    const int w    = tid >> 6;
    const int wm   = w >> 1, wn = w & 1;

    const int b = blockIdx.x & 7;        // batch == XCD (round-robin dispatch)
    // decode upper-triangular linear index -> (rt, ct), rt <= ct
    int rem = blockIdx.x >> 3, rt = 0;
    while (rem >= (NT - rt)) { rem -= (NT - rt); ++rt; }
    const int ct = rt + rem;
    const bool diag = (rt == ct);

    const char* Ag = slots + ((size_t)b * TDIM + (size_t)rt * 128) * SLOTB;
    const char* Bg = slots + ((size_t)b * TDIM + (size_t)ct * 128) * SLOTB;

    // ---- stage ALL K at once: 2048 slots per operand, 8 per thread ----
    #pragma unroll
    for (int i = 0; i < 8; ++i) {
        const int s = i*256 + tid;                   // 0..2047
        const int G = s >> 7, r = s & 127;           // granule 0..15, row 0..127
        const size_t srcoff = (size_t)r * SLOTB + G*16;
        load_lds16(Ag + srcoff, &sA[i*4096 + w*1024]);
        if (!diag)
            load_lds16(Bg + srcoff, &sB[i*4096 + w*1024]);
    }
    __syncthreads();                     // single drain: whole tile-pair resident

    f32x4 zero = {0.f, 0.f, 0.f, 0.f};
    f32x4 acc[4][4];
    #pragma unroll
    for (int m=0;m<4;++m)
        #pragma unroll
        for (int n=0;n<4;++n) acc[m][n] = zero;

    const int roff  = lane & 15;
    const int klane = lane >> 4;
    const unsigned char* Ab = &sA[0];
    const unsigned char* Bb = diag ? Ab : &sB[0];

    const i32x4 z4 = {0,0,0,0};
    #pragma unroll
    for (int ks = 0; ks < 4; ++ks) {     // 512 / 128, no barriers
        const int kbase = (ks*4 + klane) * 2048;   // granule G = ks*4 + klane
        i32x8 af[4], bf[4];
        #pragma unroll
        for (int m=0;m<4;++m) {
            i32x4 lo = *reinterpret_cast<const i32x4*>(Ab + kbase + (wm*64 + m*16 + roff)*16);
            af[m] = __builtin_shufflevector(lo, z4, 0,1,2,3,4,5,6,7);
        }
        #pragma unroll
        for (int n=0;n<4;++n) {
            i32x4 lo = *reinterpret_cast<const i32x4*>(Bb + kbase + (wn*64 + n*16 + roff)*16);
            bf[n] = __builtin_shufflevector(lo, z4, 0,1,2,3,4,5,6,7);
        }
        #pragma unroll
        for (int m=0;m<4;++m)
            #pragma unroll
            for (int n=0;n<4;++n)
                acc[m][n] = __builtin_amdgcn_mfma_scale_f32_16x16x128_f8f6f4(
                    af[m], bf[n], acc[m][n], 4, 4,   // cbsz=4 (FP4), blgp=4 (FP4)
                    0, SCALE_E8M0, 0, SCALE_E8M0);
    }

    // ---- fused epilogue ----
    // C/D layout (m89/m91, shape-determined per m128): col = lane&15, row = (lane>>4)*4 + reg
    const int gr_base = rt*128 + wm*64;
    const int gc_base = ct*128 + wn*64;
    float rmax[4][4]; // [m][reg]  row-max (diag-masked)
    float cmax[4];    // [n]       col-max (unmasked; used when rt<ct)
    #pragma unroll
    for (int n=0;n<4;++n) cmax[n] = -2.0f;
    #pragma unroll
    for (int m=0;m<4;++m) {
        #pragma unroll
        for (int r=0;r<4;++r) {
            const int grow = gr_base + m*16 + ((lane>>4)<<2) + r;
            float mx = -2.0f;
            #pragma unroll
            for (int n=0;n<4;++n) {
                const int gcol = gc_base + n*16 + (lane & 15);
                float v = acc[m][n][r];
                cmax[n] = fmaxf(cmax[n], v);
                float vm = (grow == gcol) ? -2.0f : v;
                mx = fmaxf(mx, vm);
            }
            rmax[m][r] = mx;
        }
    }
    // row-max: butterfly across the 16-lane column group
    #pragma unroll
    for (int s = 1; s < 16; s <<= 1) {
        #pragma unroll
        for (int m=0;m<4;++m)
            #pragma unroll
            for (int r=0;r<4;++r)
                rmax[m][r] = fmaxf(rmax[m][r], __shfl_xor(rmax[m][r], s, 64));
    }
    if ((lane & 15) == 0) {
        #pragma unroll
        for (int m=0;m<4;++m)
            #pragma unroll
            for (int r=0;r<4;++r)
                prow[wn][wm*64 + m*16 + ((lane>>4)<<2) + r] = rmax[m][r];
    }
    // col-max: butterfly across the 4 row-groups
    #pragma unroll
    for (int s = 16; s < 64; s <<= 1) {
        #pragma unroll
        for (int n=0;n<4;++n)
            cmax[n] = fmaxf(cmax[n], __shfl_xor(cmax[n], s, 64));
    }
    if (lane < 16) {
        #pragma unroll
        for (int n=0;n<4;++n)
            pcol[wm][wn*64 + n*16 + lane] = cmax[n];
    }
    __syncthreads();
    if (tid < 128) {
        float rv = fmaxf(prow[0][tid], prow[1][tid]);
        part[((size_t)b*NT + ct)*TDIM + (size_t)rt*128 + tid] = rv;
        if (rt != ct) {
            float cv = fmaxf(pcol[0][tid], pcol[1][tid]);
            part[((size_t)b*NT + rt)*TDIM + (size_t)ct*128 + tid] = cv;
        }
    }
}

// ---------------- kernel 3: gate * cached gelu ----------------
// slots aliases d_out: row r's slot bytes [0,256)=xq (dead), [512,1536)=gelu
// bf16. Each wave reads its own row's gelu then overwrites its own slot with
// the fp32 out row — load-before-store within the wave, race-free.
// XCD-aligned mapping: batch = blockIdx % 8.
__global__ __launch_bounds__(256) void finalize_kernel(
    char* slots,
    const float* __restrict__ part, const float* __restrict__ cosema,
    const float* __restrict__ p_log_tau, const float* __restrict__ p_log_sigma,
    const float* __restrict__ p_log_w)
{
    const int wave = threadIdx.x >> 6;
    const int lane = threadIdx.x & 63;
    const int b    = blockIdx.x & 7;          // batch == XCD
    const int ib   = blockIdx.x >> 3;         // 0..511 within batch
    const int row  = (b << 11) + ib * 4 + wave;
    const int t = row & 2047;

    const float tau   = __expf(p_log_tau[0]);
    const float sigma = log1pf(__expf(p_log_sigma[0])); // softplus
    const float wgt   = log1pf(__expf(p_log_w[0]));

    float nn = -2.0f;
    #pragma unroll
    for (int ctile = 0; ctile < NT; ++ctile)
        nn = fmaxf(nn, part[((size_t)b*NT + ctile)*TDIM + t]);
    nn = fminf(fmaxf(nn, -1.0f), 1.0f);

    const float novelty  = (1.0f - nn) * 0.5f;
    const float surprise = tanh_fast(sigma * novelty);
    const float gate = __expf(-tau * cosema[row]) * (1.0f + wgt * surprise);

    char* rowb = slots + (size_t)row * SLOTB;
    u16x8 hg = *reinterpret_cast<const u16x8*>(rowb + 512 + lane * 16);
    float4 o0, o1;
    o0.x = bf2f(hg[0]) * gate; o0.y = bf2f(hg[1]) * gate;
    o0.z = bf2f(hg[2]) * gate; o0.w = bf2f(hg[3]) * gate;
    o1.x = bf2f(hg[4]) * gate; o1.y = bf2f(hg[5]) * gate;
    o1.z = bf2f(hg[6]) * gate; o1.w = bf2f(hg[7]) * gate;
    float* orow = reinterpret_cast<float*>(rowb) + lane * 8;
    *reinterpret_cast<float4*>(orow)     = o0;
    *reinterpret_cast<float4*>(orow + 4) = o1;
}

extern "C" void kernel_launch(void* const* d_in, const int* in_sizes, int n_in,
                              void* d_out, int out_size, void* d_ws, size_t ws_size,
                              hipStream_t stream) {
    const float* x           = (const float*)d_in[0];
    // d_in[1] = logit_decay (unused by reference)
    const float* p_log_tau   = (const float*)d_in[2];
    const float* p_log_sigma = (const float*)d_in[3];
    const float* p_log_w     = (const float*)d_in[4];
    const float* ema         = (const float*)d_in[5];

    // d_out doubles as scratch: per-row 2048-B slots hold [fp4 xq | bf16 gelu]
    // until finalize overwrites each slot with the fp32 output row.
    char*  slots  = (char*)d_out;                      // B*T*SLOTB = 33.6 MB
    float* part   = (float*)d_ws;                      // B*NT*T*4 = 2 MB
    float* cosema = (float*)((char*)d_ws + (size_t)BATCH*NT*TDIM*sizeof(float));

    prep_kernel<<<dim3(BATCH*TDIM/4), 256, 0, stream>>>(x, ema, slots, cosema);
    simmax_kernel<<<dim3(NTRI*BATCH), 256, 0, stream>>>(slots, part);
    finalize_kernel<<<dim3(BATCH*TDIM/4), 256, 0, stream>>>(
        slots, part, cosema, p_log_tau, p_log_sigma, p_log_w);
}